// Round 14
// baseline (719.009 us; speedup 1.0000x reference)
//
#include <hip/hip_runtime.h>
#include <math.h>

#define NN 16000
#define EE 256000
#define GG 64
#define KK 10
#define CC 32
#define NBB 8
#define MHH 16
#define NPP 4
#define NEE 3
#define NDD 6
#define SHH 9
#define RHH 64
#define SHCC (SHH*CC)   // 288
#define NBLKN 260
#define NPADN (NBLKN*64)

typedef __attribute__((ext_vector_type(8))) short s8b;    // bf16 frag (4 VGPR)
typedef __attribute__((ext_vector_type(4))) float f32x4;  // acc frag

__device__ __forceinline__ float siluf(float x){ return x / (1.0f + __expf(-x)); }
__device__ __forceinline__ short bf16rne(float x){
  unsigned u = __float_as_uint(x);
  unsigned r = u + 0x7FFFu + ((u>>16)&1u);
  return (short)(r>>16);
}

// ---------------- init: kidx, feats[:,0,:], e0 (block-reduced), up(l=0), khist ----------------
__global__ __launch_bounds__(256) void init_kernel(
    const float* __restrict__ attrs, const float* __restrict__ E0v,
    const float* __restrict__ Wemb, const float* __restrict__ Wup0,
    const int* __restrict__ batch,
    int* __restrict__ kidx, float* __restrict__ feats, float* __restrict__ e0g,
    float* __restrict__ up, int* __restrict__ khist)
{
  __shared__ float sE0v[8];
  __shared__ int   sBv[8];
  int t = blockIdx.x*blockDim.x + threadIdx.x;
  int n = t >> 5, d = t & 31;
  const float* a = attrs + n*KK;
  int k = 0; float best = a[0];
  #pragma unroll
  for (int j=1;j<KK;j++){ float v=a[j]; if (v>best){best=v;k=j;} }
  feats[n*SHCC + d] = Wemb[k*CC+d];
  float accu = 0.0f;
  #pragma unroll
  for (int c=0;c<CC;c++) accu += Wemb[k*CC+c]*Wup0[c*CC+d];
  up[n*CC+d] = accu * 0.0625f;
  const int nn = threadIdx.x >> 5;
  if (d==0){
    kidx[n]=k;
    atomicAdd(&khist[k], 1);
    sE0v[nn]=E0v[k];
    sBv[nn]=batch[n];
  }
  __syncthreads();
  if (threadIdx.x==0){
    float acc = sE0v[0]; int b0 = sBv[0];
    #pragma unroll
    for (int i=1;i<8;i++){
      if (sBv[i]==b0) acc += sE0v[i];
      else { atomicAdd(&e0g[b0], acc); b0=sBv[i]; acc=sE0v[i]; }
    }
    atomicAdd(&e0g[b0], acc);
  }
}

// ---------------- counting sort of edges by dst ----------------
__global__ __launch_bounds__(256) void hist_kernel(
    const int* __restrict__ ei, int* __restrict__ rowptr)
{
  int e = blockIdx.x*256 + threadIdx.x;
  if (e < EE) atomicAdd(&rowptr[ei[EE+e]+1], 1);
}

__global__ __launch_bounds__(1024) void scan_kernel(
    int* __restrict__ rowptr, int* __restrict__ cursor)
{
  __shared__ int part[1024];
  const int t = threadIdx.x;
  const int SEG = 16;
  const int base = t*SEG;
  int a[SEG];
  int run = 0;
  #pragma unroll
  for (int i=0;i<SEG;i++){
    int idx = base+i;
    int v = (idx <= NN) ? rowptr[idx] : 0;
    run += v; a[i] = run;
  }
  part[t] = run;
  __syncthreads();
  for (int off=1; off<1024; off<<=1){
    int v = (t>=off) ? part[t-off] : 0;
    __syncthreads();
    part[t] += v;
    __syncthreads();
  }
  int offset = (t>0) ? part[t-1] : 0;
  #pragma unroll
  for (int i=0;i<SEG;i++){
    int idx = base+i;
    if (idx <= NN){
      int val = offset + a[i];
      rowptr[idx] = val;
      if (idx < NN) cursor[idx] = val;
    }
  }
}

__global__ __launch_bounds__(256) void scatter_kernel(
    const int* __restrict__ ei, int* __restrict__ cursor, int* __restrict__ sorted)
{
  int e = blockIdx.x*256 + threadIdx.x;
  if (e < EE){
    int d = ei[EE+e];
    int p = atomicAdd(&cursor[d], 1);
    sorted[p] = e;
  }
}

// ---------------- node k-sort: 64-aligned segments per species ----------------
__global__ void kscan_kernel(const int* __restrict__ khist, int* __restrict__ kcursor)
{
  if (threadIdx.x==0 && blockIdx.x==0){
    int off=0;
    for (int k=0;k<KK;k++){
      kcursor[k]=off;
      off += ((khist[k]+63)>>6)<<6;
    }
  }
}

__global__ __launch_bounds__(256) void kscatter_kernel(
    const int* __restrict__ kidx, int* __restrict__ kcursor, int* __restrict__ nsorted)
{
  int n = blockIdx.x*256 + threadIdx.x;
  if (n < NN){
    int p = atomicAdd(&kcursor[kidx[n]], 1);
    nsorted[p] = n;
  }
}

// ---------------- fused MFMA edge kernel: block-cooperative 64-edge windows ----------------
__global__ __launch_bounds__(256, 2) void edge_kernel(
    const float* __restrict__ pos, const float* __restrict__ shifts,
    const float* __restrict__ Wr1, const float* __restrict__ Wr2,
    const float* __restrict__ Wr3, const float* __restrict__ up,
    const int* __restrict__ ei, const int* __restrict__ sorted,
    float* __restrict__ agg)
{
  __shared__ alignas(16) short sW3T[SHCC*RHH];      // 36864 B
  __shared__ alignas(16) short sW2T[RHH*RHH];       // 8192 B
  __shared__ alignas(16) float sW1T[RHH*NBB];       // 2048 B
  __shared__ alignas(16) char  uni[64*65*4];        // 16640 B: msg | {ef, h2s}
  __shared__ alignas(16) float sh_l[4][16*12];      // 3072 B
  __shared__ int dst_l[64];                         // 256 B

  for (int i=threadIdx.x; i<RHH*SHCC; i+=256){
    int kk = i/SHCC, o = i - kk*SHCC;
    sW3T[(o*RHH + kk) ^ ((o&7)<<3)] = bf16rne(Wr3[i]);
  }
  for (int i=threadIdx.x; i<RHH*RHH; i+=256){
    int k = i>>6, kk = i&63;
    sW2T[(kk*RHH + k) ^ ((kk&7)<<3)] = bf16rne(Wr2[i]);
  }
  for (int i=threadIdx.x; i<NBB*RHH; i+=256){
    int b = i>>6, k = i&63;
    sW1T[k*NBB + b] = Wr1[i];
  }
  __syncthreads();

  const int tid  = threadIdx.x;
  const int lane = tid & 63;
  const int el   = lane & 15;
  const int r    = lane >> 4;
  const int wv   = tid >> 6;
  float* msg = (float*)uni;
  float* efw = (float*)(uni + wv*512);
  short* h2w = (short*)(uni + 2048 + wv*2304);
  float* shw = sh_l[wv];
  const f32x4 zf = {0.f,0.f,0.f,0.f};
  const float PI_ = 3.14159265358979323846f;

  for (int w = blockIdx.x; w < EE/64; w += gridDim.x) {
    const int e0 = w*64 + wv*16;
    {
      const int e = sorted[e0 + el];
      const int src = ei[e], dst = ei[EE+e];
      if (r==0) dst_l[wv*16+el] = dst;
      float x = pos[src*3+0]-pos[dst*3+0]+shifts[e*3+0];
      float y = pos[src*3+1]-pos[dst*3+1]+shifts[e*3+1];
      float z = pos[src*3+2]-pos[dst*3+2]+shifts[e*3+2];
      float rr = sqrtf(x*x+y*y+z*z+1e-12f);
      float ir = 1.0f/rr;
      x*=ir; y*=ir; z*=ir;
      const float S3=1.7320508075688772f, S5h=1.1180339887498949f;
      const float S15=3.872983346207417f, S15h=1.9364916731037085f;
      if (r==0){ shw[el*12+0]=1.0f;            shw[el*12+1]=S3*x;     shw[el*12+2]=S3*y; }
      else if (r==1){ shw[el*12+3]=S3*z;       shw[el*12+4]=S15*x*y;  shw[el*12+5]=S15*y*z; }
      else if (r==2){ shw[el*12+6]=S5h*(3.0f*z*z-1.0f); shw[el*12+7]=S15*x*z; shw[el*12+8]=S15h*(x*x-y*y); }
      float u = rr*0.2f;
      float u2=u*u, u3=u2*u, u6=u3*u3;
      float env = 1.0f - 28.0f*u6 + 48.0f*u6*u - 21.0f*u6*u2;
      env = (u<1.0f)? env : 0.0f;
      env *= ir * 0.6324555320336759f;
      float n1 = (float)(r+1), n2 = (float)(r+5);
      efw[el*8 + r]     = __sinf(n1*PI_*u)*env;
      efw[el*8 + r + 4] = __sinf(n2*PI_*u)*env;
    }
    float h1v[16];
    {
      f32x4 efa = *(const f32x4*)&efw[el*8];
      f32x4 efb = *(const f32x4*)&efw[el*8+4];
      #pragma unroll
      for (int s=0;s<2;s++){
        #pragma unroll
        for (int j=0;j<8;j++){
          int kq = 32*s + 8*r + j;
          f32x4 wa = *(const f32x4*)&sW1T[kq*NBB];
          f32x4 wb = *(const f32x4*)&sW1T[kq*NBB+4];
          float acc = efa[0]*wa[0]+efa[1]*wa[1]+efa[2]*wa[2]+efa[3]*wa[3]
                    + efb[0]*wb[0]+efb[1]*wb[1]+efb[2]*wb[2]+efb[3]*wb[3];
          h1v[s*8+j] = siluf(acc);
        }
      }
    }
    s8b a1s0, a1s1;
    #pragma unroll
    for (int j=0;j<8;j++){ a1s0[j]=bf16rne(h1v[j]); a1s1[j]=bf16rne(h1v[8+j]); }

    f32x4 aw2[4];
    #pragma unroll
    for (int t=0;t<4;t++){
      int kk = 16*t + el;
      int sw = (kk&7)<<3;
      s8b b0 = *(const s8b*)&sW2T[(kk*RHH + 8*r     ) ^ sw];
      s8b b1 = *(const s8b*)&sW2T[(kk*RHH + 8*r + 32) ^ sw];
      f32x4 acc = __builtin_amdgcn_mfma_f32_16x16x32_bf16(a1s0, b0, zf, 0,0,0);
      aw2[t]    = __builtin_amdgcn_mfma_f32_16x16x32_bf16(a1s1, b1, acc, 0,0,0);
    }
    #pragma unroll
    for (int t=0;t<4;t++){
      #pragma unroll
      for (int reg=0;reg<4;reg++)
        h2w[(4*r+reg)*72 + 16*t + el] = bf16rne(siluf(aw2[t][reg]));
    }
    s8b a2s0 = *(const s8b*)&h2w[el*72 + 8*r];
    s8b a2s1 = *(const s8b*)&h2w[el*72 + 32 + 8*r];

    float upv[4][2];
    #pragma unroll
    for (int reg=0;reg<4;reg++){
      int ee = sorted[e0 + 4*r + reg];
      int s_ = ei[ee];
      upv[reg][0] = up[s_*CC + el];
      upv[reg][1] = up[s_*CC + 16 + el];
    }
    __syncthreads();   // phase A done; ef/h2 dead; dst_l complete

    unsigned long long runmask;
    {
      bool flag = (lane==0) || (dst_l[lane] != dst_l[lane-1]);
      runmask = __ballot(flag);
    }

    #pragma unroll
    for (int c=0;c<5;c++){
      const int tBeg = 4*c;
      const int tEnd = (c<4)? (tBeg+4) : 18;
      for (int t=tBeg;t<tEnd;t++){
        int o = 16*t + el;
        int sw = (o&7)<<3;
        s8b b0 = *(const s8b*)&sW3T[(o*RHH + 8*r     ) ^ sw];
        s8b b1 = *(const s8b*)&sW3T[(o*RHH + 8*r + 32) ^ sw];
        f32x4 acc = __builtin_amdgcn_mfma_f32_16x16x32_bf16(a2s0, b0, zf, 0,0,0);
        acc       = __builtin_amdgcn_mfma_f32_16x16x32_bf16(a2s1, b1, acc, 0,0,0);
        const int sidx = t>>1, spar = t&1;
        #pragma unroll
        for (int reg=0;reg<4;reg++){
          float v = acc[reg] * shw[(4*r+reg)*12 + sidx] * upv[reg][spar];
          msg[(wv*16 + 4*r + reg)*65 + 16*(t-tBeg) + el] = v;
        }
      }
      __syncthreads();
      {
        const int col = (c<4) ? (tid & 63) : (tid & 31);
        const bool act = (c<4) || ((tid & 63) < 32);
        const int q = tid >> 6;
        const int obase = 64*c;
        if (act){
          unsigned long long m = runmask;
          int j = 0;
          while (m){
            int s = __builtin_ctzll(m);
            m &= (m-1);
            int en = m ? __builtin_ctzll(m) : 64;
            if ((j & 3) == q){
              float a = 0.0f;
              for (int i=s;i<en;i++) a += msg[i*65 + col];
              atomicAdd(agg + (size_t)dst_l[s]*SHCC + obase + col, a);
            }
            j++;
          }
        }
      }
      __syncthreads();
    }
  }
}

// ---------------- node v5: k-sorted 64-node blocks; ALL weights in LDS; v1 loop body ----------------
// Unpadded stride-32 LDS weight tiles (column access is row-per-iteration: conflict-free).
// Every weight array staged -> no loop-invariant global loads to hoist across the p-loop.
__global__ __launch_bounds__(256) void node_kernel(
    const float* __restrict__ feats, float* __restrict__ fout,
    const float* __restrict__ agg,
    const int* __restrict__ nsorted, const int* __restrict__ kidx,
    const int* __restrict__ batch,
    const float* __restrict__ Wsc, const float* __restrict__ Wprod,
    const float* __restrict__ WcL,
    const float* __restrict__ We1, const float* __restrict__ We2,
    const float* __restrict__ Wi1, const float* __restrict__ Wi2,
    const float* __restrict__ Wdp, const float* __restrict__ Wup1,
    float* __restrict__ up,
    float* __restrict__ eng, float* __restrict__ inv, float* __restrict__ dip)
{
  __shared__ float sWp[3*1024];    // 12 KB
  __shared__ float sWs[3*1024];    // 12 KB
  __shared__ float sWc[3*1024];    // 12 KB
  __shared__ float sWe[CC*MHH];    // 2 KB
  __shared__ float sWi[CC*MHH];    // 2 KB
  __shared__ float sWu[CC*CC];     // 4 KB
  __shared__ float sWd[CC*NDD];    // 0.75 KB
  __shared__ float sW2e[MHH*NEE];  // 192 B
  __shared__ float sW2i[MHH*NPP];  // 256 B
  __shared__ float s0l[8][CC];
  __shared__ float sul[8][CC];
  __shared__ float vl[8][3][CC];
  __shared__ float hl[8][CC];

  const int base = blockIdx.x*64;
  const int node0 = nsorted[base];
  if (node0 < 0) return;            // all-padding block (padding is suffix)
  const int kb = kidx[node0];

  #pragma clang loop unroll(disable)
  for (int i=threadIdx.x; i<3*1024; i+=256){
    int lv = i>>10, j = i&1023;
    sWp[i] = Wprod[i];
    sWs[i] = Wsc[(size_t)(kb*3+lv)*1024 + j];
    sWc[i] = WcL[(size_t)(lv*KK+kb)*1024 + j];
  }
  #pragma clang loop unroll(disable)
  for (int i=threadIdx.x; i<CC*MHH; i+=256){ sWe[i]=We1[i]; sWi[i]=Wi1[i]; }
  #pragma clang loop unroll(disable)
  for (int i=threadIdx.x; i<CC*CC; i+=256) sWu[i]=Wup1[i];
  if (threadIdx.x < CC*NDD) sWd[threadIdx.x]=Wdp[threadIdx.x];
  if (threadIdx.x < MHH*NEE) sW2e[threadIdx.x]=We2[threadIdx.x];
  if (threadIdx.x < MHH*NPP) sW2i[threadIdx.x]=Wi2[threadIdx.x];
  __syncthreads();

  const int t = threadIdx.x;
  const int nn = t >> 5;
  const int d = t & 31;
  const int LV[SHH] = {0,1,1,1,2,2,2,2,2};

  for (int p=0;p<8;p++){
    __syncthreads();
    const int n = nsorted[base + p*8 + nn];
    const int m = (n>=0) ? n : node0;
    const int b = (n>=0) ? batch[n] : 0;
    const float* fin = feats + (size_t)m*SHCC;
    const float* ag  = agg   + (size_t)m*SHCC;
    float nw[SHH];
    #pragma unroll
    for (int s=0;s<SHH;s++){
      const int lv = LV[s];
      const float* wp  = sWp + lv*1024 + d;
      const float* wsc = sWs + lv*1024 + d;
      float acc = 0.0f;
      #pragma unroll
      for (int c=0;c<CC;c++)
        acc += ag[s*CC+c]*wp[c*CC] + fin[s*CC+c]*wsc[c*CC];
      nw[s] = acc;
    }
    s0l[nn][d] = nw[0];
    vl[nn][0][d] = nw[1]; vl[nn][1][d] = nw[2]; vl[nn][2][d] = nw[3];
    __syncthreads();
    float corr = 0.0f;
    {
      const float* wc0 = sWc + 0*1024 + d;
      const float* wc1 = sWc + 1*1024 + d;
      const float* wc2 = sWc + 2*1024 + d;
      #pragma unroll
      for (int c=0;c<CC;c++){
        float s0 = s0l[nn][c];
        float s2 = s0*s0;
        corr += s0*wc0[c*CC] + s2*wc1[c*CC] + s2*s0*wc2[c*CC];
      }
    }
    float su = nw[0] + corr;
    sul[nn][d] = su;
    if (n>=0){
      float* fo = fout + (size_t)n*SHCC;
      fo[d] = su;
      #pragma unroll
      for (int s=1;s<SHH;s++) fo[s*CC+d] = nw[s];
    }
    __syncthreads();
    {
      const int mm = d & 15;
      const float* W = (d < MHH) ? sWe : sWi;
      float acc = 0.0f;
      #pragma unroll
      for (int c=0;c<CC;c++) acc += sul[nn][c]*W[c*MHH+mm];
      hl[nn][d] = siluf(acc);
    }
    if (n>=0){
      float acc = 0.0f;
      #pragma unroll
      for (int c=0;c<CC;c++) acc += sul[nn][c]*sWu[c*CC+d];
      up[n*CC+d] = acc * 0.0625f;
    }
    __syncthreads();
    if (n>=0){
      if (d < NEE){
        float acc=0.0f;
        #pragma unroll
        for (int mm=0;mm<MHH;mm++) acc += hl[nn][mm]*sW2e[mm*NEE+d];
        atomicAdd(&eng[b*NEE+d], acc);
      } else if (d < NEE+NPP){
        const int pp = d-NEE;
        float acc=0.0f;
        #pragma unroll
        for (int mm=0;mm<MHH;mm++) acc += hl[nn][MHH+mm]*sW2i[mm*NPP+pp];
        atomicAdd(&inv[b*NPP+pp], acc);
      } else if (d < 7+3*NDD){
        const int idx = d-7;
        const int v = idx/NDD;
        const int dd = idx - v*NDD;
        float acc=0.0f;
        #pragma unroll
        for (int c=0;c<CC;c++) acc += vl[nn][v][c]*sWd[c*NDD+dd];
        atomicAdd(&dip[(b*3+v)*NDD+dd], acc);
      }
    }
  }
}

// ---------------- final decode ----------------
__global__ __launch_bounds__(64) void final_kernel(
    const float* __restrict__ eng, const float* __restrict__ inv,
    const float* __restrict__ dip, const float* __restrict__ e0g,
    const float* __restrict__ Wd1, const float* __restrict__ bd1,
    const float* __restrict__ Wd2, const float* __restrict__ bd2,
    float* __restrict__ out)
{
  const int g = threadIdx.x;
  if (g >= GG) return;
  float e0 = e0g[g];
  float iv0=inv[g*NPP+0], iv1=inv[g*NPP+1], iv2=inv[g*NPP+2], iv3=inv[g*NPP+3];
  float o0=bd2[0], o1=bd2[1], o2=bd2[2];
  for (int m=0;m<RHH;m++){
    float hm = bd1[m] + iv0*Wd1[0*RHH+m] + iv1*Wd1[1*RHH+m] + iv2*Wd1[2*RHH+m] + iv3*Wd1[3*RHH+m];
    hm = siluf(hm);
    o0 += hm*Wd2[m*NEE+0]; o1 += hm*Wd2[m*NEE+1]; o2 += hm*Wd2[m*NEE+2];
  }
  float* og = out + g*24;
  og[0]=o0+e0; og[1]=o1+e0; og[2]=o2+e0;
  og[3]=eng[g*NEE+0]+e0; og[4]=eng[g*NEE+1]+e0; og[5]=eng[g*NEE+2]+e0;
  for (int dd=0;dd<NDD;dd++)
    for (int v=0;v<3;v++)
      og[6+dd*3+v] = dip[(g*3+v)*NDD+dd];
}

extern "C" void kernel_launch(void* const* d_in, const int* in_sizes, int n_in,
                              void* d_out, int out_size, void* d_ws, size_t ws_size,
                              hipStream_t stream)
{
  const float* pos    = (const float*)d_in[0];
  const float* attrs  = (const float*)d_in[1];
  const float* shifts = (const float*)d_in[2];
  const float* E0v    = (const float*)d_in[3];
  const float* Wemb   = (const float*)d_in[4];
  const float* Wup    = (const float*)d_in[5];
  const float* Wr1    = (const float*)d_in[6];
  const float* Wr2    = (const float*)d_in[7];
  const float* Wr3    = (const float*)d_in[8];
  const float* Wsc    = (const float*)d_in[9];
  const float* Wprod  = (const float*)d_in[10];
  const float* Wc     = (const float*)d_in[11];
  const float* We1    = (const float*)d_in[12];
  const float* We2    = (const float*)d_in[13];
  const float* Wi1    = (const float*)d_in[14];
  const float* Wi2    = (const float*)d_in[15];
  const float* Wdp    = (const float*)d_in[16];
  const float* Wd1    = (const float*)d_in[17];
  const float* bd1    = (const float*)d_in[18];
  const float* Wd2    = (const float*)d_in[19];
  const float* bd2    = (const float*)d_in[20];
  const int*   ei     = (const int*)d_in[21];
  const int*   batch  = (const int*)d_in[22];
  float* out = (float*)d_out;

  float* feats = (float*)d_ws;                 // N*288
  float* agg   = feats + (size_t)NN*SHCC;      // N*288
  float* up    = agg   + (size_t)NN*SHCC;      // N*32
  float* accum = up    + (size_t)NN*CC;        // 1664 floats + khist/kcursor
  float* e0g = accum;          // 64
  float* eng = accum + 64;     // 64*3
  float* inv = accum + 256;    // 64*4
  float* dip = accum + 512;    // 64*18
  int*   khist   = (int*)(accum + 1664);       // 16
  int*   kcursor = khist + 16;                 // 16
  int*   kidx    = kcursor + 16;               // NN
  int*   rowptr  = kidx + NN;                  // NN+1
  int*   cursor  = rowptr + NN + 1;            // NN
  int*   sorted  = cursor + NN;                // EE
  int*   nsorted = sorted + EE;                // NPADN

  hipMemsetAsync(accum, 0, (1664+32)*sizeof(float), stream);
  hipMemsetAsync(rowptr, 0, (NN+1)*sizeof(int), stream);
  hipMemsetAsync(nsorted, 0xFF, NPADN*sizeof(int), stream);
  hipMemsetAsync(feats, 0, (size_t)NN*SHCC*sizeof(float), stream);  // blit zero-fill
  init_kernel<<<(NN*CC)/256, 256, 0, stream>>>(attrs, E0v, Wemb, Wup, batch, kidx, feats, e0g, up, khist);
  hist_kernel<<<EE/256, 256, 0, stream>>>(ei, rowptr);
  scan_kernel<<<1, 1024, 0, stream>>>(rowptr, cursor);
  scatter_kernel<<<EE/256, 256, 0, stream>>>(ei, cursor, sorted);
  kscan_kernel<<<1, 64, 0, stream>>>(khist, kcursor);
  kscatter_kernel<<<(NN+255)/256, 256, 0, stream>>>(kidx, kcursor, nsorted);

  for (int l=0; l<2; ++l){
    hipMemsetAsync(agg, 0, (size_t)NN*SHCC*sizeof(float), stream);
    edge_kernel<<<512, 256, 0, stream>>>(pos, shifts,
        Wr1 + l*NBB*RHH, Wr2 + l*RHH*RHH, Wr3 + l*RHH*SHCC,
        up, ei, sorted, agg);
    node_kernel<<<NBLKN, 256, 0, stream>>>(feats, feats, agg, nsorted, kidx, batch,
        Wsc + l*KK*3*CC*CC, Wprod + l*3*CC*CC, Wc + l*3*KK*CC*CC,
        We1 + l*CC*MHH, We2 + l*MHH*NEE, Wi1 + l*CC*MHH, Wi2 + l*MHH*NPP,
        Wdp + l*CC*NDD, Wup + 1*CC*CC, up,
        eng, inv, dip);
  }
  final_kernel<<<1, 64, 0, stream>>>(eng, inv, dip, e0g, Wd1, bd1, Wd2, bd2, out);
}

// Round 15
// 656.721 us; speedup vs baseline: 1.0948x; 1.0948x over previous
//
#include <hip/hip_runtime.h>
#include <math.h>

#define NN 16000
#define EE 256000
#define GG 64
#define KK 10
#define CC 32
#define NBB 8
#define MHH 16
#define NPP 4
#define NEE 3
#define NDD 6
#define SHH 9
#define RHH 64
#define SHCC (SHH*CC)   // 288

typedef __attribute__((ext_vector_type(8))) short s8b;    // bf16 frag (4 VGPR)
typedef __attribute__((ext_vector_type(4))) float f32x4;  // acc frag

__device__ __forceinline__ float siluf(float x){ return x / (1.0f + __expf(-x)); }
__device__ __forceinline__ short bf16rne(float x){
  unsigned u = __float_as_uint(x);
  unsigned r = u + 0x7FFFu + ((u>>16)&1u);
  return (short)(r>>16);
}

// ---------------- init: kidx, feats[:,0,:], e0 (block-reduced), up(l=0) ----------------
// feats buffer is pre-zeroed by hipMemsetAsync; init writes only the s=0 channel.
__global__ __launch_bounds__(256) void init_kernel(
    const float* __restrict__ attrs, const float* __restrict__ E0v,
    const float* __restrict__ Wemb, const float* __restrict__ Wup0,
    const int* __restrict__ batch,
    int* __restrict__ kidx, float* __restrict__ feats, float* __restrict__ e0g,
    float* __restrict__ up)
{
  __shared__ float sE0v[8];
  __shared__ int   sBv[8];
  int t = blockIdx.x*blockDim.x + threadIdx.x;
  int n = t >> 5, d = t & 31;
  const float* a = attrs + n*KK;
  int k = 0; float best = a[0];
  #pragma unroll
  for (int j=1;j<KK;j++){ float v=a[j]; if (v>best){best=v;k=j;} }
  feats[n*SHCC + d] = Wemb[k*CC+d];
  float accu = 0.0f;
  #pragma unroll
  for (int c=0;c<CC;c++) accu += Wemb[k*CC+c]*Wup0[c*CC+d];
  up[n*CC+d] = accu * 0.0625f;
  const int nn = threadIdx.x >> 5;
  if (d==0){
    kidx[n]=k;
    sE0v[nn]=E0v[k];
    sBv[nn]=batch[n];
  }
  __syncthreads();
  if (threadIdx.x==0){
    float acc = sE0v[0]; int b0 = sBv[0];
    #pragma unroll
    for (int i=1;i<8;i++){
      if (sBv[i]==b0) acc += sE0v[i];
      else { atomicAdd(&e0g[b0], acc); b0=sBv[i]; acc=sE0v[i]; }
    }
    atomicAdd(&e0g[b0], acc);
  }
}

// ---------------- counting sort of edges by dst ----------------
__global__ __launch_bounds__(256) void hist_kernel(
    const int* __restrict__ ei, int* __restrict__ rowptr)
{
  int e = blockIdx.x*256 + threadIdx.x;
  if (e < EE) atomicAdd(&rowptr[ei[EE+e]+1], 1);
}

__global__ __launch_bounds__(1024) void scan_kernel(
    int* __restrict__ rowptr, int* __restrict__ cursor)
{
  __shared__ int part[1024];
  const int t = threadIdx.x;
  const int SEG = 16;
  const int base = t*SEG;
  int a[SEG];
  int run = 0;
  #pragma unroll
  for (int i=0;i<SEG;i++){
    int idx = base+i;
    int v = (idx <= NN) ? rowptr[idx] : 0;
    run += v; a[i] = run;
  }
  part[t] = run;
  __syncthreads();
  for (int off=1; off<1024; off<<=1){
    int v = (t>=off) ? part[t-off] : 0;
    __syncthreads();
    part[t] += v;
    __syncthreads();
  }
  int offset = (t>0) ? part[t-1] : 0;
  #pragma unroll
  for (int i=0;i<SEG;i++){
    int idx = base+i;
    if (idx <= NN){
      int val = offset + a[i];
      rowptr[idx] = val;
      if (idx < NN) cursor[idx] = val;
    }
  }
}

__global__ __launch_bounds__(256) void scatter_kernel(
    const int* __restrict__ ei, int* __restrict__ cursor, int* __restrict__ sorted)
{
  int e = blockIdx.x*256 + threadIdx.x;
  if (e < EE){
    int d = ei[EE+e];
    int p = atomicAdd(&cursor[d], 1);
    sorted[p] = e;
  }
}

// ---------------- fused MFMA edge kernel: block-cooperative 64-edge windows ----------------
// msg stride 68 floats: write bank (16r+4reg+el) mod 32 -> 2-way (free); was 65 -> 4-way.
__global__ __launch_bounds__(256, 2) void edge_kernel(
    const float* __restrict__ pos, const float* __restrict__ shifts,
    const float* __restrict__ Wr1, const float* __restrict__ Wr2,
    const float* __restrict__ Wr3, const float* __restrict__ up,
    const int* __restrict__ ei, const int* __restrict__ sorted,
    float* __restrict__ agg)
{
  __shared__ alignas(16) short sW3T[SHCC*RHH];      // 36864 B
  __shared__ alignas(16) short sW2T[RHH*RHH];       // 8192 B
  __shared__ alignas(16) float sW1T[RHH*NBB];       // 2048 B
  __shared__ alignas(16) char  uni[64*68*4];        // 17408 B: msg | {ef, h2s}
  __shared__ alignas(16) float sh_l[4][16*12];      // 3072 B
  __shared__ int dst_l[64];                         // 256 B

  for (int i=threadIdx.x; i<RHH*SHCC; i+=256){
    int kk = i/SHCC, o = i - kk*SHCC;
    sW3T[(o*RHH + kk) ^ ((o&7)<<3)] = bf16rne(Wr3[i]);
  }
  for (int i=threadIdx.x; i<RHH*RHH; i+=256){
    int k = i>>6, kk = i&63;
    sW2T[(kk*RHH + k) ^ ((kk&7)<<3)] = bf16rne(Wr2[i]);
  }
  for (int i=threadIdx.x; i<NBB*RHH; i+=256){
    int b = i>>6, k = i&63;
    sW1T[k*NBB + b] = Wr1[i];
  }
  __syncthreads();

  const int tid  = threadIdx.x;
  const int lane = tid & 63;
  const int el   = lane & 15;
  const int r    = lane >> 4;
  const int wv   = tid >> 6;
  float* msg = (float*)uni;
  float* efw = (float*)(uni + wv*512);
  short* h2w = (short*)(uni + 2048 + wv*2304);
  float* shw = sh_l[wv];
  const f32x4 zf = {0.f,0.f,0.f,0.f};
  const float PI_ = 3.14159265358979323846f;

  for (int w = blockIdx.x; w < EE/64; w += gridDim.x) {
    const int e0 = w*64 + wv*16;
    {
      const int e = sorted[e0 + el];
      const int src = ei[e], dst = ei[EE+e];
      if (r==0) dst_l[wv*16+el] = dst;
      float x = pos[src*3+0]-pos[dst*3+0]+shifts[e*3+0];
      float y = pos[src*3+1]-pos[dst*3+1]+shifts[e*3+1];
      float z = pos[src*3+2]-pos[dst*3+2]+shifts[e*3+2];
      float rr = sqrtf(x*x+y*y+z*z+1e-12f);
      float ir = 1.0f/rr;
      x*=ir; y*=ir; z*=ir;
      const float S3=1.7320508075688772f, S5h=1.1180339887498949f;
      const float S15=3.872983346207417f, S15h=1.9364916731037085f;
      if (r==0){ shw[el*12+0]=1.0f;            shw[el*12+1]=S3*x;     shw[el*12+2]=S3*y; }
      else if (r==1){ shw[el*12+3]=S3*z;       shw[el*12+4]=S15*x*y;  shw[el*12+5]=S15*y*z; }
      else if (r==2){ shw[el*12+6]=S5h*(3.0f*z*z-1.0f); shw[el*12+7]=S15*x*z; shw[el*12+8]=S15h*(x*x-y*y); }
      float u = rr*0.2f;
      float u2=u*u, u3=u2*u, u6=u3*u3;
      float env = 1.0f - 28.0f*u6 + 48.0f*u6*u - 21.0f*u6*u2;
      env = (u<1.0f)? env : 0.0f;
      env *= ir * 0.6324555320336759f;
      float n1 = (float)(r+1), n2 = (float)(r+5);
      efw[el*8 + r]     = __sinf(n1*PI_*u)*env;
      efw[el*8 + r + 4] = __sinf(n2*PI_*u)*env;
    }
    float h1v[16];
    {
      f32x4 efa = *(const f32x4*)&efw[el*8];
      f32x4 efb = *(const f32x4*)&efw[el*8+4];
      #pragma unroll
      for (int s=0;s<2;s++){
        #pragma unroll
        for (int j=0;j<8;j++){
          int kq = 32*s + 8*r + j;
          f32x4 wa = *(const f32x4*)&sW1T[kq*NBB];
          f32x4 wb = *(const f32x4*)&sW1T[kq*NBB+4];
          float acc = efa[0]*wa[0]+efa[1]*wa[1]+efa[2]*wa[2]+efa[3]*wa[3]
                    + efb[0]*wb[0]+efb[1]*wb[1]+efb[2]*wb[2]+efb[3]*wb[3];
          h1v[s*8+j] = siluf(acc);
        }
      }
    }
    s8b a1s0, a1s1;
    #pragma unroll
    for (int j=0;j<8;j++){ a1s0[j]=bf16rne(h1v[j]); a1s1[j]=bf16rne(h1v[8+j]); }

    f32x4 aw2[4];
    #pragma unroll
    for (int t=0;t<4;t++){
      int kk = 16*t + el;
      int sw = (kk&7)<<3;
      s8b b0 = *(const s8b*)&sW2T[(kk*RHH + 8*r     ) ^ sw];
      s8b b1 = *(const s8b*)&sW2T[(kk*RHH + 8*r + 32) ^ sw];
      f32x4 acc = __builtin_amdgcn_mfma_f32_16x16x32_bf16(a1s0, b0, zf, 0,0,0);
      aw2[t]    = __builtin_amdgcn_mfma_f32_16x16x32_bf16(a1s1, b1, acc, 0,0,0);
    }
    #pragma unroll
    for (int t=0;t<4;t++){
      #pragma unroll
      for (int reg=0;reg<4;reg++)
        h2w[(4*r+reg)*72 + 16*t + el] = bf16rne(siluf(aw2[t][reg]));
    }
    s8b a2s0 = *(const s8b*)&h2w[el*72 + 8*r];
    s8b a2s1 = *(const s8b*)&h2w[el*72 + 32 + 8*r];

    float upv[4][2];
    #pragma unroll
    for (int reg=0;reg<4;reg++){
      int ee = sorted[e0 + 4*r + reg];
      int s_ = ei[ee];
      upv[reg][0] = up[s_*CC + el];
      upv[reg][1] = up[s_*CC + 16 + el];
    }
    __syncthreads();   // phase A done; ef/h2 dead; dst_l complete

    unsigned long long runmask;
    {
      bool flag = (lane==0) || (dst_l[lane] != dst_l[lane-1]);
      runmask = __ballot(flag);
    }

    #pragma unroll
    for (int c=0;c<5;c++){
      const int tBeg = 4*c;
      const int tEnd = (c<4)? (tBeg+4) : 18;
      for (int t=tBeg;t<tEnd;t++){
        int o = 16*t + el;
        int sw = (o&7)<<3;
        s8b b0 = *(const s8b*)&sW3T[(o*RHH + 8*r     ) ^ sw];
        s8b b1 = *(const s8b*)&sW3T[(o*RHH + 8*r + 32) ^ sw];
        f32x4 acc = __builtin_amdgcn_mfma_f32_16x16x32_bf16(a2s0, b0, zf, 0,0,0);
        acc       = __builtin_amdgcn_mfma_f32_16x16x32_bf16(a2s1, b1, acc, 0,0,0);
        const int sidx = t>>1, spar = t&1;
        #pragma unroll
        for (int reg=0;reg<4;reg++){
          float v = acc[reg] * shw[(4*r+reg)*12 + sidx] * upv[reg][spar];
          msg[(wv*16 + 4*r + reg)*68 + 16*(t-tBeg) + el] = v;
        }
      }
      __syncthreads();
      {
        const int col = (c<4) ? (tid & 63) : (tid & 31);
        const bool act = (c<4) || ((tid & 63) < 32);
        const int q = tid >> 6;
        const int obase = 64*c;
        if (act){
          unsigned long long m = runmask;
          int j = 0;
          while (m){
            int s = __builtin_ctzll(m);
            m &= (m-1);
            int en = m ? __builtin_ctzll(m) : 64;
            if ((j & 3) == q){
              float a = 0.0f;
              for (int i=s;i<en;i++) a += msg[i*68 + col];
              atomicAdd(agg + (size_t)dst_l[s]*SHCC + obase + col, a);
            }
            j++;
          }
        }
      }
      __syncthreads();
    }
  }
}

// ---------------- node update + readouts + up(l+1) — proven 80-VGPR body ----------------
__global__ __launch_bounds__(256) void node_kernel(
    const float* __restrict__ feats, float* __restrict__ fout,
    const float* __restrict__ agg,
    const int* __restrict__ kidx, const int* __restrict__ batch,
    const float* __restrict__ Wsc, const float* __restrict__ Wprod,
    const float* __restrict__ WcL,
    const float* __restrict__ We1, const float* __restrict__ We2,
    const float* __restrict__ Wi1, const float* __restrict__ Wi2,
    const float* __restrict__ Wdp, const float* __restrict__ Wup1,
    float* __restrict__ up,
    float* __restrict__ eng, float* __restrict__ inv, float* __restrict__ dip)
{
  __shared__ float s0l[8][CC];
  __shared__ float sul[8][CC];
  __shared__ float vl[8][3][CC];
  __shared__ float hl[8][CC];
  const int t = threadIdx.x;
  const int nn = t >> 5;
  const int d = t & 31;
  const int n = blockIdx.x*8 + nn;
  const int k = kidx[n];
  const int b = batch[n];
  const float* fin = feats + n*SHCC;
  const float* ag = agg + n*SHCC;
  float nw[SHH];
  const int LV[SHH] = {0,1,1,1,2,2,2,2,2};
  #pragma unroll
  for (int s=0;s<SHH;s++){
    const int lv = LV[s];
    const float* wp  = Wprod + lv*CC*CC + d;
    const float* wsc = Wsc + (k*3+lv)*CC*CC + d;
    float acc = 0.0f;
    #pragma unroll
    for (int c=0;c<CC;c++)
      acc += ag[s*CC+c]*wp[c*CC] + fin[s*CC+c]*wsc[c*CC];
    nw[s] = acc;
  }
  s0l[nn][d] = nw[0];
  vl[nn][0][d] = nw[1]; vl[nn][1][d] = nw[2]; vl[nn][2][d] = nw[3];
  __syncthreads();
  float corr = 0.0f;
  {
    const float* wc0 = WcL + (0*KK+k)*CC*CC + d;
    const float* wc1 = WcL + (1*KK+k)*CC*CC + d;
    const float* wc2 = WcL + (2*KK+k)*CC*CC + d;
    #pragma unroll
    for (int c=0;c<CC;c++){
      float s0 = s0l[nn][c];
      float s2 = s0*s0;
      corr += s0*wc0[c*CC] + s2*wc1[c*CC] + s2*s0*wc2[c*CC];
    }
  }
  float su = nw[0] + corr;
  sul[nn][d] = su;
  float* fo = fout + n*SHCC;
  fo[d] = su;
  #pragma unroll
  for (int s=1;s<SHH;s++) fo[s*CC+d] = nw[s];
  __syncthreads();
  {
    const int m = d & 15;
    const float* W = (d < MHH) ? We1 : Wi1;
    float acc = 0.0f;
    #pragma unroll
    for (int c=0;c<CC;c++) acc += sul[nn][c]*W[c*MHH+m];
    hl[nn][d] = siluf(acc);
  }
  // up for next layer (folded /AVG_NBR)
  {
    float acc = 0.0f;
    #pragma unroll
    for (int c=0;c<CC;c++) acc += sul[nn][c]*Wup1[c*CC+d];
    up[n*CC+d] = acc * 0.0625f;
  }
  __syncthreads();
  if (d < NEE){
    float acc=0.0f;
    #pragma unroll
    for (int m=0;m<MHH;m++) acc += hl[nn][m]*We2[m*NEE+d];
    atomicAdd(&eng[b*NEE+d], acc);
  } else if (d < NEE+NPP){
    const int p = d-NEE;
    float acc=0.0f;
    #pragma unroll
    for (int m=0;m<MHH;m++) acc += hl[nn][MHH+m]*Wi2[m*NPP+p];
    atomicAdd(&inv[b*NPP+p], acc);
  } else if (d < 7+3*NDD){
    const int idx = d-7;
    const int v = idx/NDD;
    const int dd = idx - v*NDD;
    float acc=0.0f;
    #pragma unroll
    for (int c=0;c<CC;c++) acc += vl[nn][v][c]*Wdp[c*NDD+dd];
    atomicAdd(&dip[(b*3+v)*NDD+dd], acc);
  }
}

// ---------------- final decode ----------------
__global__ __launch_bounds__(64) void final_kernel(
    const float* __restrict__ eng, const float* __restrict__ inv,
    const float* __restrict__ dip, const float* __restrict__ e0g,
    const float* __restrict__ Wd1, const float* __restrict__ bd1,
    const float* __restrict__ Wd2, const float* __restrict__ bd2,
    float* __restrict__ out)
{
  const int g = threadIdx.x;
  if (g >= GG) return;
  float e0 = e0g[g];
  float iv0=inv[g*NPP+0], iv1=inv[g*NPP+1], iv2=inv[g*NPP+2], iv3=inv[g*NPP+3];
  float o0=bd2[0], o1=bd2[1], o2=bd2[2];
  for (int m=0;m<RHH;m++){
    float hm = bd1[m] + iv0*Wd1[0*RHH+m] + iv1*Wd1[1*RHH+m] + iv2*Wd1[2*RHH+m] + iv3*Wd1[3*RHH+m];
    hm = siluf(hm);
    o0 += hm*Wd2[m*NEE+0]; o1 += hm*Wd2[m*NEE+1]; o2 += hm*Wd2[m*NEE+2];
  }
  float* og = out + g*24;
  og[0]=o0+e0; og[1]=o1+e0; og[2]=o2+e0;
  og[3]=eng[g*NEE+0]+e0; og[4]=eng[g*NEE+1]+e0; og[5]=eng[g*NEE+2]+e0;
  for (int dd=0;dd<NDD;dd++)
    for (int v=0;v<3;v++)
      og[6+dd*3+v] = dip[(g*3+v)*NDD+dd];
}

extern "C" void kernel_launch(void* const* d_in, const int* in_sizes, int n_in,
                              void* d_out, int out_size, void* d_ws, size_t ws_size,
                              hipStream_t stream)
{
  const float* pos    = (const float*)d_in[0];
  const float* attrs  = (const float*)d_in[1];
  const float* shifts = (const float*)d_in[2];
  const float* E0v    = (const float*)d_in[3];
  const float* Wemb   = (const float*)d_in[4];
  const float* Wup    = (const float*)d_in[5];
  const float* Wr1    = (const float*)d_in[6];
  const float* Wr2    = (const float*)d_in[7];
  const float* Wr3    = (const float*)d_in[8];
  const float* Wsc    = (const float*)d_in[9];
  const float* Wprod  = (const float*)d_in[10];
  const float* Wc     = (const float*)d_in[11];
  const float* We1    = (const float*)d_in[12];
  const float* We2    = (const float*)d_in[13];
  const float* Wi1    = (const float*)d_in[14];
  const float* Wi2    = (const float*)d_in[15];
  const float* Wdp    = (const float*)d_in[16];
  const float* Wd1    = (const float*)d_in[17];
  const float* bd1    = (const float*)d_in[18];
  const float* Wd2    = (const float*)d_in[19];
  const float* bd2    = (const float*)d_in[20];
  const int*   ei     = (const int*)d_in[21];
  const int*   batch  = (const int*)d_in[22];
  float* out = (float*)d_out;

  float* feats = (float*)d_ws;                 // N*288
  float* agg   = feats + (size_t)NN*SHCC;      // N*288
  float* up    = agg   + (size_t)NN*SHCC;      // N*32
  float* accum = up    + (size_t)NN*CC;        // 1664 floats
  float* e0g = accum;          // 64
  float* eng = accum + 64;     // 64*3
  float* inv = accum + 256;    // 64*4
  float* dip = accum + 512;    // 64*18
  int*   kidx   = (int*)(accum + 1664);        // N ints
  int*   rowptr = kidx + NN;                   // NN+1 ints
  int*   cursor = rowptr + NN + 1;             // NN ints
  int*   sorted = cursor + NN;                 // EE ints

  hipMemsetAsync(accum, 0, 1664*sizeof(float), stream);
  hipMemsetAsync(rowptr, 0, (NN+1)*sizeof(int), stream);
  hipMemsetAsync(feats, 0, (size_t)NN*SHCC*sizeof(float), stream);  // blit-engine zero-fill
  init_kernel<<<(NN*CC)/256, 256, 0, stream>>>(attrs, E0v, Wemb, Wup, batch, kidx, feats, e0g, up);
  hist_kernel<<<EE/256, 256, 0, stream>>>(ei, rowptr);
  scan_kernel<<<1, 1024, 0, stream>>>(rowptr, cursor);
  scatter_kernel<<<EE/256, 256, 0, stream>>>(ei, cursor, sorted);

  for (int l=0; l<2; ++l){
    hipMemsetAsync(agg, 0, (size_t)NN*SHCC*sizeof(float), stream);
    edge_kernel<<<512, 256, 0, stream>>>(pos, shifts,
        Wr1 + l*NBB*RHH, Wr2 + l*RHH*RHH, Wr3 + l*RHH*SHCC,
        up, ei, sorted, agg);
    node_kernel<<<NN/8, 256, 0, stream>>>(feats, feats, agg, kidx, batch,
        Wsc + l*KK*3*CC*CC, Wprod + l*3*CC*CC, Wc + l*3*KK*CC*CC,
        We1 + l*CC*MHH, We2 + l*MHH*NEE, Wi1 + l*CC*MHH, Wi2 + l*MHH*NPP,
        Wdp + l*CC*NDD, Wup + 1*CC*CC, up,
        eng, inv, dip);
  }
  final_kernel<<<1, 64, 0, stream>>>(eng, inv, dip, e0g, Wd1, bd1, Wd2, bd2, out);
}

// Round 16
// 640.174 us; speedup vs baseline: 1.1231x; 1.0258x over previous
//
#include <hip/hip_runtime.h>
#include <math.h>

#define NN 16000
#define EE 256000
#define GG 64
#define KK 10
#define CC 32
#define NBB 8
#define MHH 16
#define NPP 4
#define NEE 3
#define NDD 6
#define SHH 9
#define RHH 64
#define SHCC (SHH*CC)   // 288

typedef __attribute__((ext_vector_type(8))) short s8b;    // bf16 frag (4 VGPR)
typedef __attribute__((ext_vector_type(4))) float f32x4;  // acc frag

__device__ __forceinline__ float siluf(float x){ return x / (1.0f + __expf(-x)); }
__device__ __forceinline__ short bf16rne(float x){
  unsigned u = __float_as_uint(x);
  unsigned r = u + 0x7FFFu + ((u>>16)&1u);
  return (short)(r>>16);
}

// ---------------- init: kidx, feats[:,0,:], e0 (block-reduced), up(l=0), edge hist ----------------
// feats buffer is pre-zeroed by hipMemsetAsync; init writes only the s=0 channel.
// Edge-dst histogram fused in (grid 512000 threads >= EE).
__global__ __launch_bounds__(256) void init_kernel(
    const float* __restrict__ attrs, const float* __restrict__ E0v,
    const float* __restrict__ Wemb, const float* __restrict__ Wup0,
    const int* __restrict__ batch, const int* __restrict__ ei,
    int* __restrict__ kidx, float* __restrict__ feats, float* __restrict__ e0g,
    float* __restrict__ up, int* __restrict__ rowptr)
{
  __shared__ float sE0v[8];
  __shared__ int   sBv[8];
  int t = blockIdx.x*blockDim.x + threadIdx.x;
  if (t < EE) atomicAdd(&rowptr[ei[EE+t]+1], 1);   // fused hist
  int n = t >> 5, d = t & 31;
  const float* a = attrs + n*KK;
  int k = 0; float best = a[0];
  #pragma unroll
  for (int j=1;j<KK;j++){ float v=a[j]; if (v>best){best=v;k=j;} }
  feats[n*SHCC + d] = Wemb[k*CC+d];
  float accu = 0.0f;
  #pragma unroll
  for (int c=0;c<CC;c++) accu += Wemb[k*CC+c]*Wup0[c*CC+d];
  up[n*CC+d] = accu * 0.0625f;
  const int nn = threadIdx.x >> 5;
  if (d==0){
    kidx[n]=k;
    sE0v[nn]=E0v[k];
    sBv[nn]=batch[n];
  }
  __syncthreads();
  if (threadIdx.x==0){
    float acc = sE0v[0]; int b0 = sBv[0];
    #pragma unroll
    for (int i=1;i<8;i++){
      if (sBv[i]==b0) acc += sE0v[i];
      else { atomicAdd(&e0g[b0], acc); b0=sBv[i]; acc=sE0v[i]; }
    }
    atomicAdd(&e0g[b0], acc);
  }
}

__global__ __launch_bounds__(1024) void scan_kernel(
    int* __restrict__ rowptr, int* __restrict__ cursor)
{
  __shared__ int part[1024];
  const int t = threadIdx.x;
  const int SEG = 16;
  const int base = t*SEG;
  int a[SEG];
  int run = 0;
  #pragma unroll
  for (int i=0;i<SEG;i++){
    int idx = base+i;
    int v = (idx <= NN) ? rowptr[idx] : 0;
    run += v; a[i] = run;
  }
  part[t] = run;
  __syncthreads();
  for (int off=1; off<1024; off<<=1){
    int v = (t>=off) ? part[t-off] : 0;
    __syncthreads();
    part[t] += v;
    __syncthreads();
  }
  int offset = (t>0) ? part[t-1] : 0;
  #pragma unroll
  for (int i=0;i<SEG;i++){
    int idx = base+i;
    if (idx <= NN){
      int val = offset + a[i];
      rowptr[idx] = val;
      if (idx < NN) cursor[idx] = val;
    }
  }
}

__global__ __launch_bounds__(256) void scatter_kernel(
    const int* __restrict__ ei, int* __restrict__ cursor, int* __restrict__ sorted)
{
  int e = blockIdx.x*256 + threadIdx.x;
  if (e < EE){
    int d = ei[EE+e];
    int p = atomicAdd(&cursor[d], 1);
    sorted[p] = e;
  }
}

// ---------------- fused MFMA edge kernel: block-cooperative 64-edge windows ----------------
__global__ __launch_bounds__(256, 2) void edge_kernel(
    const float* __restrict__ pos, const float* __restrict__ shifts,
    const float* __restrict__ Wr1, const float* __restrict__ Wr2,
    const float* __restrict__ Wr3, const float* __restrict__ up,
    const int* __restrict__ ei, const int* __restrict__ sorted,
    float* __restrict__ agg)
{
  __shared__ alignas(16) short sW3T[SHCC*RHH];      // 36864 B
  __shared__ alignas(16) short sW2T[RHH*RHH];       // 8192 B
  __shared__ alignas(16) float sW1T[RHH*NBB];       // 2048 B
  __shared__ alignas(16) char  uni[64*65*4];        // 16640 B: msg | {ef, h2s}
  __shared__ alignas(16) float sh_l[4][16*12];      // 3072 B
  __shared__ int dst_l[64];                         // 256 B

  for (int i=threadIdx.x; i<RHH*SHCC; i+=256){
    int kk = i/SHCC, o = i - kk*SHCC;
    sW3T[(o*RHH + kk) ^ ((o&7)<<3)] = bf16rne(Wr3[i]);
  }
  for (int i=threadIdx.x; i<RHH*RHH; i+=256){
    int k = i>>6, kk = i&63;
    sW2T[(kk*RHH + k) ^ ((kk&7)<<3)] = bf16rne(Wr2[i]);
  }
  for (int i=threadIdx.x; i<NBB*RHH; i+=256){
    int b = i>>6, k = i&63;
    sW1T[k*NBB + b] = Wr1[i];
  }
  __syncthreads();

  const int tid  = threadIdx.x;
  const int lane = tid & 63;
  const int el   = lane & 15;
  const int r    = lane >> 4;
  const int wv   = tid >> 6;
  float* msg = (float*)uni;
  float* efw = (float*)(uni + wv*512);
  short* h2w = (short*)(uni + 2048 + wv*2304);
  float* shw = sh_l[wv];
  const f32x4 zf = {0.f,0.f,0.f,0.f};
  const float PI_ = 3.14159265358979323846f;

  for (int w = blockIdx.x; w < EE/64; w += gridDim.x) {
    const int e0 = w*64 + wv*16;
    {
      const int e = sorted[e0 + el];
      const int src = ei[e], dst = ei[EE+e];
      if (r==0) dst_l[wv*16+el] = dst;
      float x = pos[src*3+0]-pos[dst*3+0]+shifts[e*3+0];
      float y = pos[src*3+1]-pos[dst*3+1]+shifts[e*3+1];
      float z = pos[src*3+2]-pos[dst*3+2]+shifts[e*3+2];
      float rr = sqrtf(x*x+y*y+z*z+1e-12f);
      float ir = 1.0f/rr;
      x*=ir; y*=ir; z*=ir;
      const float S3=1.7320508075688772f, S5h=1.1180339887498949f;
      const float S15=3.872983346207417f, S15h=1.9364916731037085f;
      if (r==0){ shw[el*12+0]=1.0f;            shw[el*12+1]=S3*x;     shw[el*12+2]=S3*y; }
      else if (r==1){ shw[el*12+3]=S3*z;       shw[el*12+4]=S15*x*y;  shw[el*12+5]=S15*y*z; }
      else if (r==2){ shw[el*12+6]=S5h*(3.0f*z*z-1.0f); shw[el*12+7]=S15*x*z; shw[el*12+8]=S15h*(x*x-y*y); }
      float u = rr*0.2f;
      float u2=u*u, u3=u2*u, u6=u3*u3;
      float env = 1.0f - 28.0f*u6 + 48.0f*u6*u - 21.0f*u6*u2;
      env = (u<1.0f)? env : 0.0f;
      env *= ir * 0.6324555320336759f;
      float n1 = (float)(r+1), n2 = (float)(r+5);
      efw[el*8 + r]     = __sinf(n1*PI_*u)*env;
      efw[el*8 + r + 4] = __sinf(n2*PI_*u)*env;
    }
    float h1v[16];
    {
      f32x4 efa = *(const f32x4*)&efw[el*8];
      f32x4 efb = *(const f32x4*)&efw[el*8+4];
      #pragma unroll
      for (int s=0;s<2;s++){
        #pragma unroll
        for (int j=0;j<8;j++){
          int kq = 32*s + 8*r + j;
          f32x4 wa = *(const f32x4*)&sW1T[kq*NBB];
          f32x4 wb = *(const f32x4*)&sW1T[kq*NBB+4];
          float acc = efa[0]*wa[0]+efa[1]*wa[1]+efa[2]*wa[2]+efa[3]*wa[3]
                    + efb[0]*wb[0]+efb[1]*wb[1]+efb[2]*wb[2]+efb[3]*wb[3];
          h1v[s*8+j] = siluf(acc);
        }
      }
    }
    s8b a1s0, a1s1;
    #pragma unroll
    for (int j=0;j<8;j++){ a1s0[j]=bf16rne(h1v[j]); a1s1[j]=bf16rne(h1v[8+j]); }

    f32x4 aw2[4];
    #pragma unroll
    for (int t=0;t<4;t++){
      int kk = 16*t + el;
      int sw = (kk&7)<<3;
      s8b b0 = *(const s8b*)&sW2T[(kk*RHH + 8*r     ) ^ sw];
      s8b b1 = *(const s8b*)&sW2T[(kk*RHH + 8*r + 32) ^ sw];
      f32x4 acc = __builtin_amdgcn_mfma_f32_16x16x32_bf16(a1s0, b0, zf, 0,0,0);
      aw2[t]    = __builtin_amdgcn_mfma_f32_16x16x32_bf16(a1s1, b1, acc, 0,0,0);
    }
    #pragma unroll
    for (int t=0;t<4;t++){
      #pragma unroll
      for (int reg=0;reg<4;reg++)
        h2w[(4*r+reg)*72 + 16*t + el] = bf16rne(siluf(aw2[t][reg]));
    }
    s8b a2s0 = *(const s8b*)&h2w[el*72 + 8*r];
    s8b a2s1 = *(const s8b*)&h2w[el*72 + 32 + 8*r];

    float upv[4][2];
    #pragma unroll
    for (int reg=0;reg<4;reg++){
      int ee = sorted[e0 + 4*r + reg];
      int s_ = ei[ee];
      upv[reg][0] = up[s_*CC + el];
      upv[reg][1] = up[s_*CC + 16 + el];
    }
    __syncthreads();   // phase A done; ef/h2 dead; dst_l complete

    unsigned long long runmask;
    {
      bool flag = (lane==0) || (dst_l[lane] != dst_l[lane-1]);
      runmask = __ballot(flag);
    }

    #pragma unroll
    for (int c=0;c<5;c++){
      const int tBeg = 4*c;
      const int tEnd = (c<4)? (tBeg+4) : 18;
      for (int t=tBeg;t<tEnd;t++){
        int o = 16*t + el;
        int sw = (o&7)<<3;
        s8b b0 = *(const s8b*)&sW3T[(o*RHH + 8*r     ) ^ sw];
        s8b b1 = *(const s8b*)&sW3T[(o*RHH + 8*r + 32) ^ sw];
        f32x4 acc = __builtin_amdgcn_mfma_f32_16x16x32_bf16(a2s0, b0, zf, 0,0,0);
        acc       = __builtin_amdgcn_mfma_f32_16x16x32_bf16(a2s1, b1, acc, 0,0,0);
        const int sidx = t>>1, spar = t&1;
        #pragma unroll
        for (int reg=0;reg<4;reg++){
          float v = acc[reg] * shw[(4*r+reg)*12 + sidx] * upv[reg][spar];
          msg[(wv*16 + 4*r + reg)*65 + 16*(t-tBeg) + el] = v;
        }
      }
      __syncthreads();
      {
        const int col = (c<4) ? (tid & 63) : (tid & 31);
        const bool act = (c<4) || ((tid & 63) < 32);
        const int q = tid >> 6;
        const int obase = 64*c;
        if (act){
          unsigned long long m = runmask;
          int j = 0;
          while (m){
            int s = __builtin_ctzll(m);
            m &= (m-1);
            int en = m ? __builtin_ctzll(m) : 64;
            if ((j & 3) == q){
              float a = 0.0f;
              for (int i=s;i<en;i++) a += msg[i*65 + col];
              atomicAdd(agg + (size_t)dst_l[s]*SHCC + obase + col, a);
            }
            j++;
          }
        }
      }
      __syncthreads();
    }
  }
}

// ---------------- node update + readouts + up(l+1) — proven 80-VGPR body ----------------
__global__ __launch_bounds__(256) void node_kernel(
    const float* __restrict__ feats, float* __restrict__ fout,
    const float* __restrict__ agg,
    const int* __restrict__ kidx, const int* __restrict__ batch,
    const float* __restrict__ Wsc, const float* __restrict__ Wprod,
    const float* __restrict__ WcL,
    const float* __restrict__ We1, const float* __restrict__ We2,
    const float* __restrict__ Wi1, const float* __restrict__ Wi2,
    const float* __restrict__ Wdp, const float* __restrict__ Wup1,
    float* __restrict__ up,
    float* __restrict__ eng, float* __restrict__ inv, float* __restrict__ dip)
{
  __shared__ float s0l[8][CC];
  __shared__ float sul[8][CC];
  __shared__ float vl[8][3][CC];
  __shared__ float hl[8][CC];
  const int t = threadIdx.x;
  const int nn = t >> 5;
  const int d = t & 31;
  const int n = blockIdx.x*8 + nn;
  const int k = kidx[n];
  const int b = batch[n];
  const float* fin = feats + n*SHCC;
  const float* ag = agg + n*SHCC;
  float nw[SHH];
  const int LV[SHH] = {0,1,1,1,2,2,2,2,2};
  #pragma unroll
  for (int s=0;s<SHH;s++){
    const int lv = LV[s];
    const float* wp  = Wprod + lv*CC*CC + d;
    const float* wsc = Wsc + (k*3+lv)*CC*CC + d;
    float acc = 0.0f;
    #pragma unroll
    for (int c=0;c<CC;c++)
      acc += ag[s*CC+c]*wp[c*CC] + fin[s*CC+c]*wsc[c*CC];
    nw[s] = acc;
  }
  s0l[nn][d] = nw[0];
  vl[nn][0][d] = nw[1]; vl[nn][1][d] = nw[2]; vl[nn][2][d] = nw[3];
  __syncthreads();
  float corr = 0.0f;
  {
    const float* wc0 = WcL + (0*KK+k)*CC*CC + d;
    const float* wc1 = WcL + (1*KK+k)*CC*CC + d;
    const float* wc2 = WcL + (2*KK+k)*CC*CC + d;
    #pragma unroll
    for (int c=0;c<CC;c++){
      float s0 = s0l[nn][c];
      float s2 = s0*s0;
      corr += s0*wc0[c*CC] + s2*wc1[c*CC] + s2*s0*wc2[c*CC];
    }
  }
  float su = nw[0] + corr;
  sul[nn][d] = su;
  float* fo = fout + n*SHCC;
  fo[d] = su;
  #pragma unroll
  for (int s=1;s<SHH;s++) fo[s*CC+d] = nw[s];
  __syncthreads();
  {
    const int m = d & 15;
    const float* W = (d < MHH) ? We1 : Wi1;
    float acc = 0.0f;
    #pragma unroll
    for (int c=0;c<CC;c++) acc += sul[nn][c]*W[c*MHH+m];
    hl[nn][d] = siluf(acc);
  }
  // up for next layer (folded /AVG_NBR)
  {
    float acc = 0.0f;
    #pragma unroll
    for (int c=0;c<CC;c++) acc += sul[nn][c]*Wup1[c*CC+d];
    up[n*CC+d] = acc * 0.0625f;
  }
  __syncthreads();
  if (d < NEE){
    float acc=0.0f;
    #pragma unroll
    for (int m=0;m<MHH;m++) acc += hl[nn][m]*We2[m*NEE+d];
    atomicAdd(&eng[b*NEE+d], acc);
  } else if (d < NEE+NPP){
    const int p = d-NEE;
    float acc=0.0f;
    #pragma unroll
    for (int m=0;m<MHH;m++) acc += hl[nn][MHH+m]*Wi2[m*NPP+p];
    atomicAdd(&inv[b*NPP+p], acc);
  } else if (d < 7+3*NDD){
    const int idx = d-7;
    const int v = idx/NDD;
    const int dd = idx - v*NDD;
    float acc=0.0f;
    #pragma unroll
    for (int c=0;c<CC;c++) acc += vl[nn][v][c]*Wdp[c*NDD+dd];
    atomicAdd(&dip[(b*3+v)*NDD+dd], acc);
  }
}

// ---------------- final decode ----------------
__global__ __launch_bounds__(64) void final_kernel(
    const float* __restrict__ eng, const float* __restrict__ inv,
    const float* __restrict__ dip, const float* __restrict__ e0g,
    const float* __restrict__ Wd1, const float* __restrict__ bd1,
    const float* __restrict__ Wd2, const float* __restrict__ bd2,
    float* __restrict__ out)
{
  const int g = threadIdx.x;
  if (g >= GG) return;
  float e0 = e0g[g];
  float iv0=inv[g*NPP+0], iv1=inv[g*NPP+1], iv2=inv[g*NPP+2], iv3=inv[g*NPP+3];
  float o0=bd2[0], o1=bd2[1], o2=bd2[2];
  for (int m=0;m<RHH;m++){
    float hm = bd1[m] + iv0*Wd1[0*RHH+m] + iv1*Wd1[1*RHH+m] + iv2*Wd1[2*RHH+m] + iv3*Wd1[3*RHH+m];
    hm = siluf(hm);
    o0 += hm*Wd2[m*NEE+0]; o1 += hm*Wd2[m*NEE+1]; o2 += hm*Wd2[m*NEE+2];
  }
  float* og = out + g*24;
  og[0]=o0+e0; og[1]=o1+e0; og[2]=o2+e0;
  og[3]=eng[g*NEE+0]+e0; og[4]=eng[g*NEE+1]+e0; og[5]=eng[g*NEE+2]+e0;
  for (int dd=0;dd<NDD;dd++)
    for (int v=0;v<3;v++)
      og[6+dd*3+v] = dip[(g*3+v)*NDD+dd];
}

extern "C" void kernel_launch(void* const* d_in, const int* in_sizes, int n_in,
                              void* d_out, int out_size, void* d_ws, size_t ws_size,
                              hipStream_t stream)
{
  const float* pos    = (const float*)d_in[0];
  const float* attrs  = (const float*)d_in[1];
  const float* shifts = (const float*)d_in[2];
  const float* E0v    = (const float*)d_in[3];
  const float* Wemb   = (const float*)d_in[4];
  const float* Wup    = (const float*)d_in[5];
  const float* Wr1    = (const float*)d_in[6];
  const float* Wr2    = (const float*)d_in[7];
  const float* Wr3    = (const float*)d_in[8];
  const float* Wsc    = (const float*)d_in[9];
  const float* Wprod  = (const float*)d_in[10];
  const float* Wc     = (const float*)d_in[11];
  const float* We1    = (const float*)d_in[12];
  const float* We2    = (const float*)d_in[13];
  const float* Wi1    = (const float*)d_in[14];
  const float* Wi2    = (const float*)d_in[15];
  const float* Wdp    = (const float*)d_in[16];
  const float* Wd1    = (const float*)d_in[17];
  const float* bd1    = (const float*)d_in[18];
  const float* Wd2    = (const float*)d_in[19];
  const float* bd2    = (const float*)d_in[20];
  const int*   ei     = (const int*)d_in[21];
  const int*   batch  = (const int*)d_in[22];
  float* out = (float*)d_out;

  float* feats = (float*)d_ws;                 // N*288
  float* agg   = feats + (size_t)NN*SHCC;      // N*288
  float* up    = agg   + (size_t)NN*SHCC;      // N*32
  float* accum = up    + (size_t)NN*CC;        // 1664 floats
  float* e0g = accum;          // 64
  float* eng = accum + 64;     // 64*3
  float* inv = accum + 256;    // 64*4
  float* dip = accum + 512;    // 64*18
  int*   rowptr = (int*)(accum + 1664);        // NN+1 ints (adjacent: one memset covers accum+rowptr)
  int*   kidx   = rowptr + NN + 1;             // NN ints
  int*   cursor = kidx + NN;                   // NN ints
  int*   sorted = cursor + NN;                 // EE ints

  hipMemsetAsync(accum, 0, (1664 + NN + 1)*sizeof(float), stream);          // accum + rowptr in one call
  hipMemsetAsync(feats, 0, (size_t)NN*SHCC*sizeof(float), stream);          // blit-engine zero-fill
  init_kernel<<<(NN*CC)/256, 256, 0, stream>>>(attrs, E0v, Wemb, Wup, batch, ei,
                                               kidx, feats, e0g, up, rowptr);
  scan_kernel<<<1, 1024, 0, stream>>>(rowptr, cursor);
  scatter_kernel<<<EE/256, 256, 0, stream>>>(ei, cursor, sorted);

  for (int l=0; l<2; ++l){
    hipMemsetAsync(agg, 0, (size_t)NN*SHCC*sizeof(float), stream);
    edge_kernel<<<512, 256, 0, stream>>>(pos, shifts,
        Wr1 + l*NBB*RHH, Wr2 + l*RHH*RHH, Wr3 + l*RHH*SHCC,
        up, ei, sorted, agg);
    node_kernel<<<NN/8, 256, 0, stream>>>(feats, feats, agg, kidx, batch,
        Wsc + l*KK*3*CC*CC, Wprod + l*3*CC*CC, Wc + l*3*KK*CC*CC,
        We1 + l*CC*MHH, We2 + l*MHH*NEE, Wi1 + l*CC*MHH, Wi2 + l*MHH*NPP,
        Wdp + l*CC*NDD, Wup + 1*CC*CC, up,
        eng, inv, dip);
  }
  final_kernel<<<1, 64, 0, stream>>>(eng, inv, dip, e0g, Wd1, bd1, Wd2, bd2, out);
}